// Round 1
// baseline (46.636 us; speedup 1.0000x reference)
//
#include <hip/hip_runtime.h>

#define BLOCK 256
#define MAX_LDS_CENTERS 4096

__global__ __launch_bounds__(BLOCK) void sinusoidal_kernel(
    const float* __restrict__ t,
    const float* __restrict__ weights,
    const float* __restrict__ c_ptr,
    const int*   __restrict__ nc_ptr,
    float*       __restrict__ out,
    int n4, int n)
{
    __shared__ float ws[MAX_LDS_CENTERS];

    const int   nc    = nc_ptr[0];
    const float c     = c_ptr[0];
    const float inv_c = 1.0f / c;
    const float PI_F  = 3.14159265358979f;

    const bool use_lds = (nc <= MAX_LDS_CENTERS);
    if (use_lds) {
        for (int i = threadIdx.x; i < nc; i += BLOCK) ws[i] = weights[i];
    }
    __syncthreads();

    const bool pow2 = ((nc & (nc - 1)) == 0);
    const int  mask = nc - 1;
    const float* __restrict__ wtab = use_lds ? ws : weights;

    const int tid    = blockIdx.x * BLOCK + threadIdx.x;
    const int stride = gridDim.x * BLOCK;

    const float4* __restrict__ t4 = reinterpret_cast<const float4*>(t);
    float4*       __restrict__ o4 = reinterpret_cast<float4*>(out);

    for (int i = tid; i < n4; i += stride) {
        float4 tv = t4[i];
        float xin[4] = {tv.x, tv.y, tv.z, tv.w};
        float os[4];
        #pragma unroll
        for (int j = 0; j < 4; ++j) {
            float x  = xin[j] * inv_c;
            float bf = floorf(x);
            float fr = x - bf;                 // in [0,1)
            float s  = __sinf(PI_F * fr);      // small-arg fast sin
            int bin  = (int)bf;                // t >= 0 so floor==trunc ok
            s = (bin & 1) ? -s : s;            // (-1)^bin
            int widx = bin >> 1;
            widx = pow2 ? (widx & mask) : (widx % nc);
            os[j] = wtab[widx] * s;
        }
        float4 ov;
        ov.x = os[0]; ov.y = os[1]; ov.z = os[2]; ov.w = os[3];
        o4[i] = ov;
    }

    // scalar tail (n not divisible by 4)
    int tail_start = n4 * 4;
    for (int i = tail_start + tid; i < n; i += stride) {
        float x  = t[i] * inv_c;
        float bf = floorf(x);
        float fr = x - bf;
        float s  = __sinf(PI_F * fr);
        int bin  = (int)bf;
        s = (bin & 1) ? -s : s;
        int widx = bin >> 1;
        widx = pow2 ? (widx & mask) : (widx % nc);
        out[i] = wtab[widx] * s;
    }
}

extern "C" void kernel_launch(void* const* d_in, const int* in_sizes, int n_in,
                              void* d_out, int out_size, void* d_ws, size_t ws_size,
                              hipStream_t stream) {
    const float* t  = (const float*)d_in[0];
    const float* w  = (const float*)d_in[1];
    const float* c  = (const float*)d_in[2];
    const int*   nc = (const int*)d_in[3];
    float* out = (float*)d_out;

    int n  = in_sizes[0];
    int n4 = n / 4;

    int grid = (n4 + BLOCK - 1) / BLOCK;
    if (grid > 2048) grid = 2048;
    if (grid < 1) grid = 1;

    sinusoidal_kernel<<<grid, BLOCK, 0, stream>>>(t, w, c, nc, out, n4, n);
}